// Round 3
// baseline (266.554 us; speedup 1.0000x reference)
//
#include <hip/hip_runtime.h>

#define LUT_N 4096
#define DVAL  4096
#define TPB   256

static constexpr double TWO_PI_D = 6.283185307179586476925286766559;
#define PHI_F 1.61803398874989484820f

typedef float f32x4_t __attribute__((ext_vector_type(4)));

// ---------- helpers ----------
__device__ __forceinline__ float fc(const float4& f, int j) {
    switch (j) { case 0: return f.x; case 1: return f.y; case 2: return f.z; }
    return f.w;
}
__device__ __forceinline__ void sc4(float4& f, int j, float v) {
    switch (j) { case 0: f.x = v; return; case 1: f.y = v; return; case 2: f.z = v; return; }
    f.w = v;
}
// jnp: idx = mod(round(theta*(N/2pi)).astype(int32), N). rintf = round-half-even,
// &(N-1) = Python mod for pow2. IEEE ops only, no reassociation/contract changes.
__device__ __forceinline__ int lut_index(float theta, float cidx) {
    return ((int)rintf(theta * cidx)) & (LUT_N - 1);
}
__device__ __forceinline__ void nt_store4(float4 v, float4* p) {
    f32x4_t w; w.x = v.x; w.y = v.y; w.z = v.z; w.w = v.w;
    __builtin_nontemporal_store(w, (f32x4_t*)p);
}

// ---------- precompute: LUT + per-column derived params ----------
__global__ __launch_bounds__(TPB) void echo_precompute(
    const float* __restrict__ w_query,
    const float* __restrict__ w_out,
    const float* __restrict__ beta,
    float2* __restrict__ lut,   // [LUT_N] {sin, cos}
    float*  __restrict__ wlq,   // [D] 1+|w_query|
    float*  __restrict__ wlo,   // [D] 1+|w_out|
    float*  __restrict__ wsc)   // [D] w_eff*(1-decay)
{
    int i = blockIdx.x * TPB + threadIdx.x;
    const float c2 = (float)(TWO_PI_D / (double)LUT_N);
    if (i < LUT_N) {
        float ang = (float)i * c2;               // matches arange(N)*(2pi/N) in f32
        lut[i] = make_float2(sinf(ang), cosf(ang));
    }
    if (i < DVAL) {
        float wavelength_q = 1.0f + fabsf(w_query[i]);
        float wavelength   = 1.0f + fabsf(w_out[i]);
        float beta_eff = 1.0f / (1.0f + fabsf(beta[i]));
        float w_eff    = 1.0f / wavelength;      // 1/(1+|w_out|), same subexpr as ref
        float decay    = fminf(expf(-beta_eff * w_eff), 0.9999f);
        wlq[i] = wavelength_q;
        wlo[i] = wavelength;
        wsc[i] = w_eff * (1.0f - decay);
    }
}

// ---------- main fused kernel: one block per batch row ----------
template<bool USE_WS>
__global__ __launch_bounds__(TPB) void echo_main(
    const float* __restrict__ x_real,
    const float* __restrict__ x_imag,
    const float* __restrict__ t,
    const float* __restrict__ trig_r,
    const float* __restrict__ trig_i,
    const float* __restrict__ w_query,
    const float* __restrict__ b_query,
    const float* __restrict__ w_out,
    const float* __restrict__ b_out,
    const float* __restrict__ beta,
    const float2* __restrict__ lutG,
    const float*  __restrict__ wlqG,
    const float*  __restrict__ wloG,
    const float*  __restrict__ wscG,
    float* __restrict__ out,
    int B)
{
    __shared__ float2 lutS[LUT_N];
    __shared__ float redR[4], redI[4];
    __shared__ float magS;

    const int tid = threadIdx.x;
    const int b   = blockIdx.x;
    const float cidx = (float)((double)LUT_N / TWO_PI_D);  // 651.89865f

    // stage the LUT into LDS
    if constexpr (USE_WS) {
        const float4* src = (const float4*)lutG;
        float4* dst = (float4*)lutS;
        #pragma unroll
        for (int k = 0; k < 8; ++k) {
            int idx = tid + TPB * k;      // 2048 float4 = 4096 float2
            dst[idx] = src[idx];
        }
    } else {
        const float c2 = (float)(TWO_PI_D / (double)LUT_N);
        #pragma unroll
        for (int k = 0; k < 16; ++k) {
            int idx = tid + TPB * k;
            float ang = (float)idx * c2;
            lutS[idx] = make_float2(sinf(ang), cosf(ang));
        }
    }

    const float tphi = t[b] * PHI_F;
    const float* xr = x_real + (size_t)b * DVAL;
    const float* xi = x_imag + (size_t)b * DVAL;

    float4 xr_s[4], xi_s[4];
    float accr = 0.0f, acci = 0.0f;

    __syncthreads();

    // ---- stage 1: per-head interference, reduced over the whole row ----
    // q_real+i*q_imag = exp(i*(theta_r+theta_i)) on the quantized LUT grid:
    // cos_r*cos_i - sin_r*sin_i == cos((ir+ii)*step) to ~4e-7 -> single gather.
    #pragma unroll
    for (int k = 0; k < 4; ++k) {
        int v = tid + TPB * k;            // float4 index within row
        float4 a = ((const float4*)xr)[v];
        float4 c = ((const float4*)xi)[v];
        xr_s[k] = a; xi_s[k] = c;

        float4 wl4;
        if constexpr (USE_WS) {
            wl4 = ((const float4*)wlqG)[v];
        } else {
            float4 wq4 = ((const float4*)w_query)[v];
            wl4 = make_float4(1.0f + fabsf(wq4.x), 1.0f + fabsf(wq4.y),
                              1.0f + fabsf(wq4.z), 1.0f + fabsf(wq4.w));
        }
        float4 bq4 = ((const float4*)b_query)[v];
        float4 tr4 = ((const float4*)trig_r)[v];
        float4 ti4 = ((const float4*)trig_i)[v];

        #pragma unroll
        for (int j = 0; j < 4; ++j) {
            float wl = fc(wl4, j), bq = fc(bq4, j);
            float thr = fc(a, j) / wl + bq + tphi;   // exact ref op order
            float thi = fc(c, j) / wl + bq + tphi;
            int ir = lut_index(thr, cidx);
            int ii = lut_index(thi, cidx);
            float2 s = lutS[(ir + ii) & (LUT_N - 1)];  // {sin, cos} of sum
            float q_r = s.y, q_i = s.x;
            accr += q_r * fc(tr4, j) + q_i * fc(ti4, j);
            acci += q_r * fc(ti4, j) - q_i * fc(tr4, j);
        }
    }

    // ---- block reduction -> int_mag ----
    #pragma unroll
    for (int m = 32; m >= 1; m >>= 1) {
        accr += __shfl_xor(accr, m, 64);
        acci += __shfl_xor(acci, m, 64);
    }
    if ((tid & 63) == 0) { redR[tid >> 6] = accr; redI[tid >> 6] = acci; }
    __syncthreads();
    if (tid == 0) {
        float tr = (redR[0] + redR[1] + redR[2] + redR[3]) * 0.0625f; // mean over 16 heads
        float ti = (redI[0] + redI[1] + redI[2] + redI[3]) * 0.0625f;
        magS = sqrtf(tr * tr + ti * ti + 1e-8f);
    }
    __syncthreads();
    const float mag = magS;

    // ---- stage 2: memory write + Euler projection ----
    float4* outR = (float4*)(out + (size_t)b * DVAL);
    float4* outI = (float4*)(out + (size_t)B * DVAL + (size_t)b * DVAL);

    #pragma unroll
    for (int k = 0; k < 4; ++k) {
        int v = tid + TPB * k;
        float4 wl4, ws4;
        if constexpr (USE_WS) {
            wl4 = ((const float4*)wloG)[v];
            ws4 = ((const float4*)wscG)[v];
        } else {
            float4 wo4 = ((const float4*)w_out)[v];
            float4 be4 = ((const float4*)beta)[v];
            #pragma unroll
            for (int j = 0; j < 4; ++j) {
                float wavelength = 1.0f + fabsf(fc(wo4, j));
                float beta_eff = 1.0f / (1.0f + fabsf(fc(be4, j)));
                float w_eff = 1.0f / wavelength;
                float decay = fminf(expf(-beta_eff * w_eff), 0.9999f);
                sc4(wl4, j, wavelength);
                sc4(ws4, j, w_eff * (1.0f - decay));
            }
        }
        float4 bo4 = ((const float4*)b_out)[v];

        float4 oR, oI;
        #pragma unroll
        for (int j = 0; j < 4; ++j) {
            float ws = fc(ws4, j), wl = fc(wl4, j), bo = fc(bo4, j);
            float mr = (fc(xr_s[k], j) * mag) * ws;   // x*int_mag*write_scale, left-assoc
            float mi = (fc(xi_s[k], j) * mag) * ws;
            float thr = mr / wl + bo + tphi;
            float thi = mi / wl + bo + tphi;
            int ir = lut_index(thr, cidx);
            int ii = lut_index(thi, cidx);
            float2 s = lutS[(ir + ii) & (LUT_N - 1)];
            sc4(oR, j, s.y);   // cos(sum) = cos_or*cos_oi - sin_or*sin_oi
            sc4(oI, j, s.x);   // sin(sum) = cos_or*sin_oi + sin_or*cos_oi
        }
        nt_store4(oR, &outR[v]);   // write-once stream: keep L2 for LUT/params
        nt_store4(oI, &outI[v]);
    }
}

extern "C" void kernel_launch(void* const* d_in, const int* in_sizes, int n_in,
                              void* d_out, int out_size, void* d_ws, size_t ws_size,
                              hipStream_t stream) {
    const float* x_real    = (const float*)d_in[0];
    const float* x_imag    = (const float*)d_in[1];
    const float* t         = (const float*)d_in[2];
    const float* trig_r    = (const float*)d_in[3];
    const float* trig_i    = (const float*)d_in[4];
    const float* w_query   = (const float*)d_in[5];
    const float* b_query   = (const float*)d_in[6];
    const float* w_out     = (const float*)d_in[7];
    const float* b_out     = (const float*)d_in[8];
    const float* beta      = (const float*)d_in[9];
    float* out = (float*)d_out;

    const int B = in_sizes[2];          // 4096
    const size_t need = (size_t)LUT_N * sizeof(float2) + 3 * (size_t)DVAL * sizeof(float);

    if (d_ws != nullptr && ws_size >= need) {
        char* ws = (char*)d_ws;
        float2* lut = (float2*)ws;
        float*  wlq = (float*)(ws + (size_t)LUT_N * sizeof(float2));
        float*  wlo = wlq + DVAL;
        float*  wsc = wlo + DVAL;
        echo_precompute<<<(LUT_N > DVAL ? LUT_N : DVAL) / TPB, TPB, 0, stream>>>(
            w_query, w_out, beta, lut, wlq, wlo, wsc);
        echo_main<true><<<B, TPB, 0, stream>>>(
            x_real, x_imag, t, trig_r, trig_i, w_query, b_query, w_out, b_out, beta,
            lut, wlq, wlo, wsc, out, B);
    } else {
        echo_main<false><<<B, TPB, 0, stream>>>(
            x_real, x_imag, t, trig_r, trig_i, w_query, b_query, w_out, b_out, beta,
            nullptr, nullptr, nullptr, nullptr, out, B);
    }
}

// Round 7
// 265.731 us; speedup vs baseline: 1.0031x; 1.0031x over previous
//
#include <hip/hip_runtime.h>

#define LUT_N 4096
#define DVAL  4096
#define TPB   512    // 2 rows per block: 32 KB LUT amortized over 8 waves -> 100% occupancy

static constexpr double TWO_PI_D = 6.283185307179586476925286766559;
#define PHI_F 1.61803398874989484820f

typedef float f32x4_t __attribute__((ext_vector_type(4)));

// ---------- helpers ----------
__device__ __forceinline__ float fc(const float4& f, int j) {
    switch (j) { case 0: return f.x; case 1: return f.y; case 2: return f.z; }
    return f.w;
}
__device__ __forceinline__ void sc4(float4& f, int j, float v) {
    switch (j) { case 0: f.x = v; return; case 1: f.y = v; return; case 2: f.z = v; return; }
    f.w = v;
}
// jnp: idx = mod(round(theta*(N/2pi)).astype(int32), N). rintf = round-half-even,
// &(N-1) = Python mod for pow2. IEEE ops only, no reassociation/contract changes.
__device__ __forceinline__ int lut_index(float theta, float cidx) {
    return ((int)rintf(theta * cidx)) & (LUT_N - 1);
}
__device__ __forceinline__ void nt_store4(float4 v, float4* p) {
    f32x4_t w; w.x = v.x; w.y = v.y; w.z = v.z; w.w = v.w;
    __builtin_nontemporal_store(w, (f32x4_t*)p);
}

// ---------- precompute: LUT + per-column derived params ----------
__global__ __launch_bounds__(256) void echo_precompute(
    const float* __restrict__ w_query,
    const float* __restrict__ w_out,
    const float* __restrict__ beta,
    float2* __restrict__ lut,   // [LUT_N] {sin, cos}
    float*  __restrict__ wlq,   // [D] 1+|w_query|
    float*  __restrict__ wlo,   // [D] 1+|w_out|
    float*  __restrict__ wsc)   // [D] w_eff*(1-decay)
{
    int i = blockIdx.x * 256 + threadIdx.x;
    const float c2 = (float)(TWO_PI_D / (double)LUT_N);
    if (i < LUT_N) {
        float ang = (float)i * c2;               // matches arange(N)*(2pi/N) in f32
        lut[i] = make_float2(sinf(ang), cosf(ang));
    }
    if (i < DVAL) {
        float wavelength_q = 1.0f + fabsf(w_query[i]);
        float wavelength   = 1.0f + fabsf(w_out[i]);
        float beta_eff = 1.0f / (1.0f + fabsf(beta[i]));
        float w_eff    = 1.0f / wavelength;      // 1/(1+|w_out|), same subexpr as ref
        float decay    = fminf(expf(-beta_eff * w_eff), 0.9999f);
        wlq[i] = wavelength_q;
        wlo[i] = wavelength;
        wsc[i] = w_eff * (1.0f - decay);
    }
}

// ---------- main fused kernel: one block = TWO batch rows (waves 0-3 / 4-7) ----------
template<bool USE_WS>
__global__ __launch_bounds__(TPB, 8) void echo_main(
    const float* __restrict__ x_real,
    const float* __restrict__ x_imag,
    const float* __restrict__ t,
    const float* __restrict__ trig_r,
    const float* __restrict__ trig_i,
    const float* __restrict__ w_query,
    const float* __restrict__ b_query,
    const float* __restrict__ w_out,
    const float* __restrict__ b_out,
    const float* __restrict__ beta,
    const float2* __restrict__ lutG,
    const float*  __restrict__ wlqG,
    const float*  __restrict__ wloG,
    const float*  __restrict__ wscG,
    float* __restrict__ out,
    int B)
{
    __shared__ float2 lutS[LUT_N];   // 32 KB, shared by both rows
    __shared__ float redR[8], redI[8];
    __shared__ float magS[2];

    const int tid  = threadIdx.x;
    const int half = tid >> 8;             // 0: first row, 1: second row
    const int lane = tid & 255;            // thread index within the row
    int row = blockIdx.x * 2 + half;
    if (row >= B) row = B - 1;             // odd-B safety: duplicate last row (same output)
    const float cidx = (float)((double)LUT_N / TWO_PI_D);  // 651.89865f

    // stage the LUT into LDS (512 threads x 4 float4 = 2048 float4 = 4096 float2)
    if constexpr (USE_WS) {
        const float4* src = (const float4*)lutG;
        float4* dst = (float4*)lutS;
        #pragma unroll
        for (int k = 0; k < 4; ++k) {
            int idx = tid + TPB * k;
            dst[idx] = src[idx];
        }
    } else {
        const float c2 = (float)(TWO_PI_D / (double)LUT_N);
        #pragma unroll
        for (int k = 0; k < 8; ++k) {
            int idx = tid + TPB * k;
            float ang = (float)idx * c2;
            lutS[idx] = make_float2(sinf(ang), cosf(ang));
        }
    }

    const float tphi = t[row] * PHI_F;
    const float* xr = x_real + (size_t)row * DVAL;
    const float* xi = x_imag + (size_t)row * DVAL;

    float4 xr_s[4], xi_s[4];
    float accr = 0.0f, acci = 0.0f;

    __syncthreads();

    // ---- stage 1: per-head interference, reduced over the whole row ----
    // q_real+i*q_imag = exp(i*(theta_r+theta_i)) on the quantized LUT grid:
    // cos_r*cos_i - sin_r*sin_i == cos((ir+ii)*step) -> single float2 gather.
    #pragma unroll
    for (int k = 0; k < 4; ++k) {
        int v = lane + 256 * k;            // float4 index within row (1024 per row)
        float4 a = ((const float4*)xr)[v];
        float4 c = ((const float4*)xi)[v];
        xr_s[k] = a; xi_s[k] = c;

        float4 wl4;
        if constexpr (USE_WS) {
            wl4 = ((const float4*)wlqG)[v];
        } else {
            float4 wq4 = ((const float4*)w_query)[v];
            wl4 = make_float4(1.0f + fabsf(wq4.x), 1.0f + fabsf(wq4.y),
                              1.0f + fabsf(wq4.z), 1.0f + fabsf(wq4.w));
        }
        float4 bq4 = ((const float4*)b_query)[v];
        float4 tr4 = ((const float4*)trig_r)[v];
        float4 ti4 = ((const float4*)trig_i)[v];

        #pragma unroll
        for (int j = 0; j < 4; ++j) {
            float wl = fc(wl4, j), bq = fc(bq4, j);
            float thr = fc(a, j) / wl + bq + tphi;   // exact ref op order
            float thi = fc(c, j) / wl + bq + tphi;
            int ir = lut_index(thr, cidx);
            int ii = lut_index(thi, cidx);
            float2 s = lutS[(ir + ii) & (LUT_N - 1)];  // {sin, cos} of sum
            float q_r = s.y, q_i = s.x;
            accr += q_r * fc(tr4, j) + q_i * fc(ti4, j);
            acci += q_r * fc(ti4, j) - q_i * fc(tr4, j);
        }
    }

    // ---- per-row block reduction -> int_mag ----
    #pragma unroll
    for (int m = 32; m >= 1; m >>= 1) {
        accr += __shfl_xor(accr, m, 64);
        acci += __shfl_xor(acci, m, 64);
    }
    const int wave = tid >> 6;             // 0..7; waves 0-3 = row A, 4-7 = row B
    if ((tid & 63) == 0) { redR[wave] = accr; redI[wave] = acci; }
    __syncthreads();
    if (lane == 0) {                       // tid==0 and tid==256
        int o = half * 4;
        float tr = (redR[o] + redR[o+1] + redR[o+2] + redR[o+3]) * 0.0625f; // mean over 16 heads
        float ti = (redI[o] + redI[o+1] + redI[o+2] + redI[o+3]) * 0.0625f;
        magS[half] = sqrtf(tr * tr + ti * ti + 1e-8f);
    }
    __syncthreads();
    const float mag = magS[half];

    // ---- stage 2: memory write + Euler projection ----
    float4* outR = (float4*)(out + (size_t)row * DVAL);
    float4* outI = (float4*)(out + (size_t)B * DVAL + (size_t)row * DVAL);

    #pragma unroll
    for (int k = 0; k < 4; ++k) {
        int v = lane + 256 * k;
        float4 wl4, ws4;
        if constexpr (USE_WS) {
            wl4 = ((const float4*)wloG)[v];
            ws4 = ((const float4*)wscG)[v];
        } else {
            float4 wo4 = ((const float4*)w_out)[v];
            float4 be4 = ((const float4*)beta)[v];
            #pragma unroll
            for (int j = 0; j < 4; ++j) {
                float wavelength = 1.0f + fabsf(fc(wo4, j));
                float beta_eff = 1.0f / (1.0f + fabsf(fc(be4, j)));
                float w_eff = 1.0f / wavelength;
                float decay = fminf(expf(-beta_eff * w_eff), 0.9999f);
                sc4(wl4, j, wavelength);
                sc4(ws4, j, w_eff * (1.0f - decay));
            }
        }
        float4 bo4 = ((const float4*)b_out)[v];

        float4 oR, oI;
        #pragma unroll
        for (int j = 0; j < 4; ++j) {
            float ws = fc(ws4, j), wl = fc(wl4, j), bo = fc(bo4, j);
            float mr = (fc(xr_s[k], j) * mag) * ws;   // x*int_mag*write_scale, left-assoc
            float mi = (fc(xi_s[k], j) * mag) * ws;
            float thr = mr / wl + bo + tphi;
            float thi = mi / wl + bo + tphi;
            int ir = lut_index(thr, cidx);
            int ii = lut_index(thi, cidx);
            float2 s = lutS[(ir + ii) & (LUT_N - 1)];
            sc4(oR, j, s.y);   // cos(sum) = cos_or*cos_oi - sin_or*sin_oi
            sc4(oI, j, s.x);   // sin(sum) = cos_or*sin_oi + sin_or*cos_oi
        }
        nt_store4(oR, &outR[v]);   // write-once stream: keep L2 for LUT/params
        nt_store4(oI, &outI[v]);
    }
}

extern "C" void kernel_launch(void* const* d_in, const int* in_sizes, int n_in,
                              void* d_out, int out_size, void* d_ws, size_t ws_size,
                              hipStream_t stream) {
    const float* x_real    = (const float*)d_in[0];
    const float* x_imag    = (const float*)d_in[1];
    const float* t         = (const float*)d_in[2];
    const float* trig_r    = (const float*)d_in[3];
    const float* trig_i    = (const float*)d_in[4];
    const float* w_query   = (const float*)d_in[5];
    const float* b_query   = (const float*)d_in[6];
    const float* w_out     = (const float*)d_in[7];
    const float* b_out     = (const float*)d_in[8];
    const float* beta      = (const float*)d_in[9];
    float* out = (float*)d_out;

    const int B = in_sizes[2];          // 4096
    const int nblocks = (B + 1) / 2;    // 2 rows per block
    const size_t need = (size_t)LUT_N * sizeof(float2) + 3 * (size_t)DVAL * sizeof(float);

    if (d_ws != nullptr && ws_size >= need) {
        char* ws = (char*)d_ws;
        float2* lut = (float2*)ws;
        float*  wlq = (float*)(ws + (size_t)LUT_N * sizeof(float2));
        float*  wlo = wlq + DVAL;
        float*  wsc = wlo + DVAL;
        echo_precompute<<<(LUT_N > DVAL ? LUT_N : DVAL) / 256, 256, 0, stream>>>(
            w_query, w_out, beta, lut, wlq, wlo, wsc);
        echo_main<true><<<nblocks, TPB, 0, stream>>>(
            x_real, x_imag, t, trig_r, trig_i, w_query, b_query, w_out, b_out, beta,
            lut, wlq, wlo, wsc, out, B);
    } else {
        echo_main<false><<<nblocks, TPB, 0, stream>>>(
            x_real, x_imag, t, trig_r, trig_i, w_query, b_query, w_out, b_out, beta,
            nullptr, nullptr, nullptr, nullptr, out, B);
    }
}

// Round 8
// 260.624 us; speedup vs baseline: 1.0228x; 1.0196x over previous
//
#include <hip/hip_runtime.h>

#define LUT_N 4096
#define DVAL  4096
#define TPB   512    // 2 rows per block: 32 KB LUT amortized over 8 waves

static constexpr double TWO_PI_D = 6.283185307179586476925286766559;
#define PHI_F 1.61803398874989484820f

typedef float f32x4_t __attribute__((ext_vector_type(4)));

// ---------- helpers ----------
__device__ __forceinline__ float fc(const float4& f, int j) {
    switch (j) { case 0: return f.x; case 1: return f.y; case 2: return f.z; }
    return f.w;
}
__device__ __forceinline__ void sc4(float4& f, int j, float v) {
    switch (j) { case 0: f.x = v; return; case 1: f.y = v; return; case 2: f.z = v; return; }
    f.w = v;
}
// jnp: idx = mod(round(theta*(N/2pi)).astype(int32), N). rintf = round-half-even,
// single final & 4095 == Python mod for pow2 (valid since (a&m + b&m)&m == (a+b)&m).
__device__ __forceinline__ int lut_round(float theta, float cidx) {
    return (int)rintf(theta * cidx);
}
__device__ __forceinline__ void nt_store4(float4 v, float4* p) {
    f32x4_t w; w.x = v.x; w.y = v.y; w.z = v.z; w.w = v.w;
    __builtin_nontemporal_store(w, (f32x4_t*)p);
}

// ---------- precompute: LUT + per-column reciprocals (kills per-element IEEE divides) ----------
__global__ __launch_bounds__(256) void echo_precompute(
    const float* __restrict__ w_query,
    const float* __restrict__ w_out,
    const float* __restrict__ beta,
    float2* __restrict__ lut,   // [LUT_N] {sin, cos}
    float*  __restrict__ invq,  // [D] 1/(1+|w_query|)
    float*  __restrict__ wsi)   // [D] (w_eff*(1-decay)) * (1/wavelength) = write_scale/wavelength
{
    int i = blockIdx.x * 256 + threadIdx.x;
    const float c2 = (float)(TWO_PI_D / (double)LUT_N);
    if (i < LUT_N) {
        float ang = (float)i * c2;               // matches arange(N)*(2pi/N) in f32
        lut[i] = make_float2(sinf(ang), cosf(ang));
    }
    if (i < DVAL) {
        float inv_q     = 1.0f / (1.0f + fabsf(w_query[i]));   // IEEE divide, once per column
        float w_eff     = 1.0f / (1.0f + fabsf(w_out[i]));
        float beta_eff  = 1.0f / (1.0f + fabsf(beta[i]));
        float decay     = fminf(expf(-beta_eff * w_eff), 0.9999f);
        invq[i] = inv_q;
        wsi[i]  = (w_eff * (1.0f - decay)) * w_eff;            // write_scale * (1/wavelength)
    }
}

// ---------- main fused kernel: one block = TWO batch rows (waves 0-3 / 4-7) ----------
template<bool USE_WS>
__global__ __launch_bounds__(TPB, 8) void echo_main(
    const float* __restrict__ x_real,
    const float* __restrict__ x_imag,
    const float* __restrict__ t,
    const float* __restrict__ trig_r,
    const float* __restrict__ trig_i,
    const float* __restrict__ w_query,
    const float* __restrict__ b_query,
    const float* __restrict__ w_out,
    const float* __restrict__ b_out,
    const float* __restrict__ beta,
    const float2* __restrict__ lutG,
    const float*  __restrict__ invqG,
    const float*  __restrict__ wsiG,
    float* __restrict__ out,
    int B)
{
    __shared__ float2 lutS[LUT_N];   // 32 KB, shared by both rows
    __shared__ float redR[8], redI[8];
    __shared__ float magS[2];

    const int tid  = threadIdx.x;
    const int half = tid >> 8;             // 0: first row, 1: second row
    const int lane = tid & 255;            // thread index within the row
    int row = blockIdx.x * 2 + half;
    if (row >= B) row = B - 1;             // odd-B safety: duplicate last row (same output)
    const float cidx = (float)((double)LUT_N / TWO_PI_D);  // 651.89865f

    // stage the LUT into LDS (512 threads x 4 float4 = 2048 float4 = 4096 float2)
    if constexpr (USE_WS) {
        const float4* src = (const float4*)lutG;
        float4* dst = (float4*)lutS;
        #pragma unroll
        for (int k = 0; k < 4; ++k) {
            int idx = tid + TPB * k;
            dst[idx] = src[idx];
        }
    } else {
        const float c2 = (float)(TWO_PI_D / (double)LUT_N);
        #pragma unroll
        for (int k = 0; k < 8; ++k) {
            int idx = tid + TPB * k;
            float ang = (float)idx * c2;
            lutS[idx] = make_float2(sinf(ang), cosf(ang));
        }
    }

    const float tphi = t[row] * PHI_F;
    const float* xr = x_real + (size_t)row * DVAL;
    const float* xi = x_imag + (size_t)row * DVAL;

    float4 xr_s[4], xi_s[4];
    float accr = 0.0f, acci = 0.0f;

    __syncthreads();

    // ---- stage 1: per-head interference, reduced over the whole row ----
    // q_real+i*q_imag = exp(i*(theta_r+theta_i)) on the quantized LUT grid:
    // cos_r*cos_i - sin_r*sin_i == cos((ir+ii)*step) -> single float2 gather.
    #pragma unroll
    for (int k = 0; k < 4; ++k) {
        int v = lane + 256 * k;            // float4 index within row (1024 per row)
        float4 a = ((const float4*)xr)[v];
        float4 c = ((const float4*)xi)[v];
        xr_s[k] = a; xi_s[k] = c;

        float4 iv4;
        if constexpr (USE_WS) {
            iv4 = ((const float4*)invqG)[v];
        } else {
            float4 wq4 = ((const float4*)w_query)[v];
            iv4 = make_float4(1.0f / (1.0f + fabsf(wq4.x)), 1.0f / (1.0f + fabsf(wq4.y)),
                              1.0f / (1.0f + fabsf(wq4.z)), 1.0f / (1.0f + fabsf(wq4.w)));
        }
        float4 bq4 = ((const float4*)b_query)[v];
        float4 tr4 = ((const float4*)trig_r)[v];
        float4 ti4 = ((const float4*)trig_i)[v];

        #pragma unroll
        for (int j = 0; j < 4; ++j) {
            float iv = fc(iv4, j), bq = fc(bq4, j);
            // x/wl -> x*inv (<=2ulp of IEEE div); fma(x,inv,bq)+tphi keeps the
            // dominant-add order of the reference ((x/wl)+bq)+tphi.
            float thr = __builtin_fmaf(fc(a, j), iv, bq) + tphi;
            float thi = __builtin_fmaf(fc(c, j), iv, bq) + tphi;
            int idx = (lut_round(thr, cidx) + lut_round(thi, cidx)) & (LUT_N - 1);
            float2 s = lutS[idx];          // {sin, cos} of angle sum
            float q_r = s.y, q_i = s.x;
            accr = __builtin_fmaf(q_r, fc(tr4, j), __builtin_fmaf(q_i, fc(ti4, j), accr));
            acci = __builtin_fmaf(q_r, fc(ti4, j), __builtin_fmaf(-q_i, fc(tr4, j), acci));
        }
    }

    // ---- per-row block reduction -> int_mag ----
    #pragma unroll
    for (int m = 32; m >= 1; m >>= 1) {
        accr += __shfl_xor(accr, m, 64);
        acci += __shfl_xor(acci, m, 64);
    }
    const int wave = tid >> 6;             // 0..7; waves 0-3 = row A, 4-7 = row B
    if ((tid & 63) == 0) { redR[wave] = accr; redI[wave] = acci; }
    __syncthreads();
    if (lane == 0) {                       // tid==0 and tid==256
        int o = half * 4;
        float tr = (redR[o] + redR[o+1] + redR[o+2] + redR[o+3]) * 0.0625f; // mean over 16 heads
        float ti = (redI[o] + redI[o+1] + redI[o+2] + redI[o+3]) * 0.0625f;
        magS[half] = sqrtf(tr * tr + ti * ti + 1e-8f);
    }
    __syncthreads();
    const float mag = magS[half];

    // ---- stage 2: memory write + Euler projection ----
    float4* outR = (float4*)(out + (size_t)row * DVAL);
    float4* outI = (float4*)(out + (size_t)B * DVAL + (size_t)row * DVAL);

    #pragma unroll
    for (int k = 0; k < 4; ++k) {
        int v = lane + 256 * k;
        float4 ws4;
        if constexpr (USE_WS) {
            ws4 = ((const float4*)wsiG)[v];
        } else {
            float4 wo4 = ((const float4*)w_out)[v];
            float4 be4 = ((const float4*)beta)[v];
            #pragma unroll
            for (int j = 0; j < 4; ++j) {
                float w_eff = 1.0f / (1.0f + fabsf(fc(wo4, j)));
                float beta_eff = 1.0f / (1.0f + fabsf(fc(be4, j)));
                float decay = fminf(expf(-beta_eff * w_eff), 0.9999f);
                sc4(ws4, j, (w_eff * (1.0f - decay)) * w_eff);
            }
        }
        float4 bo4 = ((const float4*)b_out)[v];

        float4 oR, oI;
        #pragma unroll
        for (int j = 0; j < 4; ++j) {
            float wsi_j = fc(ws4, j), bo = fc(bo4, j);
            // mem/wl = ((x*mag)*ws)/wl -> (x*mag)*(ws/wl) (<=~2.5ulp); term is tiny
            // (|mem/wl| << tphi) so index perturbation is negligible.
            float xmr = fc(xr_s[k], j) * mag;
            float xmi = fc(xi_s[k], j) * mag;
            float thr = __builtin_fmaf(xmr, wsi_j, bo) + tphi;
            float thi = __builtin_fmaf(xmi, wsi_j, bo) + tphi;
            int idx = (lut_round(thr, cidx) + lut_round(thi, cidx)) & (LUT_N - 1);
            float2 s = lutS[idx];
            sc4(oR, j, s.y);   // cos(sum) = cos_or*cos_oi - sin_or*sin_oi
            sc4(oI, j, s.x);   // sin(sum) = cos_or*sin_oi + sin_or*cos_oi
        }
        nt_store4(oR, &outR[v]);   // write-once stream: keep L2/L3 for LUT/params
        nt_store4(oI, &outI[v]);
    }
}

extern "C" void kernel_launch(void* const* d_in, const int* in_sizes, int n_in,
                              void* d_out, int out_size, void* d_ws, size_t ws_size,
                              hipStream_t stream) {
    const float* x_real    = (const float*)d_in[0];
    const float* x_imag    = (const float*)d_in[1];
    const float* t         = (const float*)d_in[2];
    const float* trig_r    = (const float*)d_in[3];
    const float* trig_i    = (const float*)d_in[4];
    const float* w_query   = (const float*)d_in[5];
    const float* b_query   = (const float*)d_in[6];
    const float* w_out     = (const float*)d_in[7];
    const float* b_out     = (const float*)d_in[8];
    const float* beta      = (const float*)d_in[9];
    float* out = (float*)d_out;

    const int B = in_sizes[2];          // 4096
    const int nblocks = (B + 1) / 2;    // 2 rows per block
    const size_t need = (size_t)LUT_N * sizeof(float2) + 2 * (size_t)DVAL * sizeof(float);

    if (d_ws != nullptr && ws_size >= need) {
        char* ws = (char*)d_ws;
        float2* lut  = (float2*)ws;
        float*  invq = (float*)(ws + (size_t)LUT_N * sizeof(float2));
        float*  wsi  = invq + DVAL;
        echo_precompute<<<(LUT_N > DVAL ? LUT_N : DVAL) / 256, 256, 0, stream>>>(
            w_query, w_out, beta, lut, invq, wsi);
        echo_main<true><<<nblocks, TPB, 0, stream>>>(
            x_real, x_imag, t, trig_r, trig_i, w_query, b_query, w_out, b_out, beta,
            lut, invq, wsi, out, B);
    } else {
        echo_main<false><<<nblocks, TPB, 0, stream>>>(
            x_real, x_imag, t, trig_r, trig_i, w_query, b_query, w_out, b_out, beta,
            nullptr, nullptr, nullptr, out, B);
    }
}